// Round 11
// baseline (247.241 us; speedup 1.0000x reference)
//
#include <hip/hip_runtime.h>
#include <math.h>

#define ALPHA 0.2f
#define LOG2E 1.44269504089f

typedef __attribute__((ext_vector_type(8))) short bf16x8;
typedef __attribute__((ext_vector_type(4))) float f32x4;

__device__ __forceinline__ float elu1(float x)  { return x > 0.f ? x : (__expf(x) - 1.f); }

// round-to-nearest-even f32 -> bf16 (finite values only)
__device__ __forceinline__ unsigned short f2bf(float x) {
    unsigned u = __float_as_uint(x);
    return (unsigned short)((u + 0x7fffu + ((u >> 16) & 1u)) >> 16);
}
__device__ __forceinline__ unsigned pkbf16(float a, float b) {
    return (unsigned)f2bf(a) | ((unsigned)f2bf(b) << 16);
}
__device__ __forceinline__ float bfs(unsigned short v) { return __uint_as_float((unsigned)v << 16); }

// ---------------------------------------------------------------------------
// Prep (single launch): blocks 0..287 transpose weights (W [z][K][128] f32 ->
// WT [z][128][K] bf16 via LDS 64x64 tiles; z<8: Wh K=256, z==8: Wo K=1024);
// blocks 288..2335 convert x f32 -> bf16 (1024 elems each).
// ---------------------------------------------------------------------------
__global__ __launch_bounds__(256) void prep_all(
    const float* __restrict__ x, const float* __restrict__ Wh,
    const float* __restrict__ Wo, unsigned short* __restrict__ xb,
    unsigned short* __restrict__ WhT, unsigned short* __restrict__ WoT)
{
    __shared__ float T[64][65];
    const int tid = threadIdx.x;
    const int gid = blockIdx.x;

    if (gid >= 288) {                 // x convert
        int idx = (gid - 288) * 1024 + tid * 4;
        float4 v = *(const float4*)(x + idx);
        uint2 o = make_uint2(pkbf16(v.x, v.y), pkbf16(v.z, v.w));
        *(uint2*)(xb + idx) = o;
        return;
    }

    const int z = gid >> 5, rem = gid & 31;
    const int bx = rem & 15, by = rem >> 4;
    const int K = (z < 8) ? 256 : 1024;
    if (bx * 64 >= K) return;
    const float* in = (z < 8) ? (Wh + (size_t)z * K * 128) : Wo;
    unsigned short* out = (z < 8) ? (WhT + (size_t)z * 128 * K) : WoT;
    const int k0 = bx * 64, n0 = by * 64;

    const int kr = tid >> 4, nc = (tid & 15) * 4;
#pragma unroll
    for (int s = 0; s < 4; ++s) {
        float4 v = *(const float4*)(in + (size_t)(k0 + kr + s * 16) * 128 + n0 + nc);
        T[kr + s * 16][nc]     = v.x;
        T[kr + s * 16][nc + 1] = v.y;
        T[kr + s * 16][nc + 2] = v.z;
        T[kr + s * 16][nc + 3] = v.w;
    }
    __syncthreads();
    const int nr0 = tid >> 3, kc = (tid & 7) * 8;
#pragma unroll
    for (int s = 0; s < 2; ++s) {
        int nr = nr0 + s * 32;
        unsigned pk[4];
#pragma unroll
        for (int q = 0; q < 4; ++q)
            pk[q] = pkbf16(T[kc + 2 * q][nr], T[kc + 2 * q + 1][nr]);
        *(uint4*)(out + (size_t)(n0 + nr) * K + k0 + kc) = make_uint4(pk[0], pk[1], pk[2], pk[3]);
    }
}

// ---------------------------------------------------------------------------
// LDS-staged bf16 MFMA GEMM with transposed C store (C^T via aliased LDS ->
// coalesced uint4 stores). DOF=1 (BN==128): fused f1/f2 dot-products.
// ---------------------------------------------------------------------------
template <int BM, int BN, int WM, int WN, int DOF>
__global__ __launch_bounds__(256) void gemm_t(
    const unsigned short* __restrict__ A, const unsigned short* __restrict__ Bt,
    unsigned short* __restrict__ Ct, int K,
    const float* __restrict__ aV, float* __restrict__ f1g, float* __restrict__ f2g)
{
    const int RM = WM / 16, RN = WN / 16;
    const int NCA = BM * 8 / 256, NCB = BN * 8 / 256;
    __shared__ __align__(16) unsigned short SAB[(BM + BN) * 72];
    unsigned short (*As)[72] = (unsigned short(*)[72])SAB;
    unsigned short (*Bs)[72] = (unsigned short(*)[72])(SAB + BM * 72);
    unsigned short (*Cs)[BM + 8] = (unsigned short(*)[BM + 8])SAB;   // alias
    float* redf = (float*)(SAB + BN * (BM + 8));                     // after Cs

    const int tid = threadIdx.x;
    const int w = tid >> 6, lane = tid & 63;
    const int n16 = lane & 15, quad = lane >> 4;
    const int WX = BM / WM;
    const int wm = (w % WX) * WM, wn = (w / WX) * WN;
    const int m0 = blockIdx.x * BM, n0 = blockIdx.y * BN;

    f32x4 acc[RM][RN];
#pragma unroll
    for (int mm = 0; mm < RM; ++mm)
#pragma unroll
        for (int nn = 0; nn < RN; ++nn) acc[mm][nn] = (f32x4){0.f, 0.f, 0.f, 0.f};

    uint4 ra[NCA], rb[NCB];
#pragma unroll
    for (int i = 0; i < NCA; ++i) {
        int c = tid * NCA + i, r = c >> 3, cc = (c & 7) * 8;
        ra[i] = *(const uint4*)(A + (size_t)(m0 + r) * K + cc);
    }
#pragma unroll
    for (int i = 0; i < NCB; ++i) {
        int c = tid * NCB + i, r = c >> 3, cc = (c & 7) * 8;
        rb[i] = *(const uint4*)(Bt + (size_t)(n0 + r) * K + cc);
    }

    const int nk = K >> 6;
    for (int kt = 0; kt < nk; ++kt) {
        __syncthreads();
#pragma unroll
        for (int i = 0; i < NCA; ++i) {
            int c = tid * NCA + i, r = c >> 3, cc = (c & 7) * 8;
            *(uint4*)&As[r][cc] = ra[i];
        }
#pragma unroll
        for (int i = 0; i < NCB; ++i) {
            int c = tid * NCB + i, r = c >> 3, cc = (c & 7) * 8;
            *(uint4*)&Bs[r][cc] = rb[i];
        }
        __syncthreads();
        if (kt + 1 < nk) {
            int k0 = (kt + 1) * 64;
#pragma unroll
            for (int i = 0; i < NCA; ++i) {
                int c = tid * NCA + i, r = c >> 3, cc = (c & 7) * 8;
                ra[i] = *(const uint4*)(A + (size_t)(m0 + r) * K + k0 + cc);
            }
#pragma unroll
            for (int i = 0; i < NCB; ++i) {
                int c = tid * NCB + i, r = c >> 3, cc = (c & 7) * 8;
                rb[i] = *(const uint4*)(Bt + (size_t)(n0 + r) * K + k0 + cc);
            }
        }
#pragma unroll
        for (int ks = 0; ks < 2; ++ks) {
            bf16x8 am[RM], bn[RN];
#pragma unroll
            for (int mm = 0; mm < RM; ++mm)
                am[mm] = *(const bf16x8*)&As[wm + mm * 16 + n16][ks * 32 + quad * 8];
#pragma unroll
            for (int nn = 0; nn < RN; ++nn)
                bn[nn] = *(const bf16x8*)&Bs[wn + nn * 16 + n16][ks * 32 + quad * 8];
#pragma unroll
            for (int mm = 0; mm < RM; ++mm)
#pragma unroll
                for (int nn = 0; nn < RN; ++nn)
                    acc[mm][nn] = __builtin_amdgcn_mfma_f32_16x16x32_bf16(
                        am[mm], bn[nn], acc[mm][nn], 0, 0, 0);
        }
    }

    __syncthreads();   // all LDS frag reads done before Cs aliases As/Bs

#pragma unroll
    for (int nn = 0; nn < RN; ++nn) {
        int n = wn + nn * 16 + n16;
#pragma unroll
        for (int mm = 0; mm < RM; ++mm) {
            int m = wm + mm * 16 + quad * 4;
            f32x4 a = acc[mm][nn];
            ushort4 o = make_ushort4(f2bf(a[0]), f2bf(a[1]), f2bf(a[2]), f2bf(a[3]));
            *(ushort4*)&Cs[n][m] = o;
        }
    }
    __syncthreads();

    const int CHUNKS = BM * 2 / 16;
    const int RPP = 256 / CHUNKS;
    const int row = tid / CHUNKS, ch = tid % CHUNKS;
#pragma unroll
    for (int s = 0; s < BN / RPP; ++s) {
        int n = row + s * RPP;
        *(uint4*)(Ct + (size_t)(n0 + n) * 8192 + m0 + ch * 8) =
            *(const uint4*)&Cs[n][ch * 8];
    }

    if (DOF) {
        const int mloc = tid & 63, fq = tid >> 6;
        const float* az = aV + blockIdx.y * 256;
        float s1 = 0.f, s2 = 0.f;
#pragma unroll 8
        for (int k = 0; k < 32; ++k) {
            int f = fq * 32 + k;
            float h = bfs(Cs[f][mloc]);
            s1 += h * az[f];
            s2 += h * az[128 + f];
        }
        *(float2*)&redf[(fq * 64 + mloc) * 2] = make_float2(s1, s2);
        __syncthreads();
        if (tid < 64) {
            float a1 = redf[tid * 2]       + redf[(64 + tid) * 2]
                     + redf[(128 + tid) * 2] + redf[(192 + tid) * 2];
            float a2 = redf[tid * 2 + 1]       + redf[(64 + tid) * 2 + 1]
                     + redf[(128 + tid) * 2 + 1] + redf[(192 + tid) * 2 + 1];
            f1g[(size_t)blockIdx.y * 8192 + m0 + tid] = a1;
            f2g[(size_t)blockIdx.y * 8192 + m0 + tid] = a2;
        }
    }
}

// ---------------------------------------------------------------------------
// sort_prep: one block per (h,b) slice. Exact softmax reformulation:
// p_ij = max(Ai*u_j, A2i*v_j), branch switches at f2_j >= -f1_i (exact:
// (1-a)(f1+f2) >= 0). Sort j by f2L ascending (bitonic, LDS); u=exp2(f2L),
// v=exp2(a*f2L); scalar exclusive prefixes give l_i exactly. Outputs per
// slice: inverse permutation, (u,v) per rank, threshold rank t_i, and
// coefficients (Ai/l_i, A2i/l_i).
// ---------------------------------------------------------------------------
__global__ __launch_bounds__(256) void sort_prep(
    const float* __restrict__ f1g, const float* __restrict__ f2g,
    unsigned short* __restrict__ invS, float2* __restrict__ uvS,
    unsigned short* __restrict__ tS, float2* __restrict__ cS)
{
    __shared__ float key[1024];
    __shared__ unsigned short val[1024];
    __shared__ float2 pref[1025];
    __shared__ float2 segT[256];

    const int tid = threadIdx.x;
    const size_t base = (size_t)blockIdx.x * 1024;

#pragma unroll
    for (int e = 0; e < 4; ++e) {
        int r = tid + 256 * e;
        key[r] = f2g[base + r] * LOG2E;
        val[r] = (unsigned short)r;
    }
    // bitonic sort ascending
    for (int k = 2; k <= 1024; k <<= 1) {
        for (int j = k >> 1; j > 0; j >>= 1) {
            __syncthreads();
#pragma unroll
            for (int e = 0; e < 4; ++e) {
                int idx = tid + 256 * e;
                int ixj = idx ^ j;
                if (ixj > idx) {
                    bool up = ((idx & k) == 0);
                    float a = key[idx], b = key[ixj];
                    if ((a > b) == up) {
                        key[idx] = b; key[ixj] = a;
                        unsigned short tv = val[idx]; val[idx] = val[ixj]; val[ixj] = tv;
                    }
                }
            }
        }
    }
    __syncthreads();

    // u/v tables + exclusive prefix (float2), plus inverse permutation
    float2 s = make_float2(0.f, 0.f);
#pragma unroll
    for (int e = 0; e < 4; ++e) {
        int r = tid * 4 + e;
        float kk = key[r];
        float2 x = make_float2(__builtin_amdgcn_exp2f(kk),
                               __builtin_amdgcn_exp2f(ALPHA * kk));
        uvS[base + r] = x;
        pref[r] = s;
        s.x += x.x; s.y += x.y;
    }
    segT[tid] = s;
#pragma unroll
    for (int e = 0; e < 4; ++e) {
        int r = tid + 256 * e;
        invS[base + val[r]] = (unsigned short)r;
    }
    __syncthreads();
    if (tid < 64) {
        float2 tmp[4], loc[4];
        float2 s2 = make_float2(0.f, 0.f);
#pragma unroll
        for (int e = 0; e < 4; ++e) tmp[e] = segT[tid * 4 + e];
#pragma unroll
        for (int e = 0; e < 4; ++e) { loc[e] = s2; s2.x += tmp[e].x; s2.y += tmp[e].y; }
        float ix = s2.x, iy = s2.y;
#pragma unroll
        for (int off = 1; off < 64; off <<= 1) {
            float nx = __shfl_up(ix, off);
            float ny = __shfl_up(iy, off);
            if (tid >= off) { ix += nx; iy += ny; }
        }
        float ex = ix - s2.x, ey = iy - s2.y;
#pragma unroll
        for (int e = 0; e < 4; ++e)
            segT[tid * 4 + e] = make_float2(loc[e].x + ex, loc[e].y + ey);
        if (tid == 63) pref[1024] = make_float2(ix, iy);
    }
    __syncthreads();
    {
        float2 off = segT[tid];
#pragma unroll
        for (int e = 0; e < 4; ++e) {
            int r = tid * 4 + e;
            pref[r].x += off.x; pref[r].y += off.y;
        }
    }
    __syncthreads();

    const float f2mL = key[1023];
    const float2 tot = pref[1024];
#pragma unroll
    for (int e = 0; e < 4; ++e) {
        int i = tid + 256 * e;
        float f1L = f1g[base + i] * LOG2E;
        float thr = -f1L;
        int lo = 0, hi = 1024;
        while (lo < hi) { int mid = (lo + hi) >> 1; if (key[mid] < thr) lo = mid + 1; else hi = mid; }
        float ss = f1L + f2mL;
        float mc = fmaxf(ss, ALPHA * ss);
        float Ai = __builtin_amdgcn_exp2f(f1L - mc);
        float A2 = __builtin_amdgcn_exp2f(ALPHA * f1L - mc);
        float2 pt = pref[lo];
        float l = Ai * (tot.x - pt.x) + A2 * pt.y;
        float inv = 1.f / l;
        tS[base + i] = (unsigned short)lo;
        cS[base + i] = make_float2(Ai * inv, A2 * inv);
    }
}

// ---------------------------------------------------------------------------
// attn_sorted: block = (slice, 8-feature chunk). O(N*F) exact attention:
// out[i][f] = act( cA_i*(CuTot[f]-Cu[t_i][f]) + cB_i*Cv[t_i][f] )
// where Cu/Cv are exclusive prefix sums (over sorted ranks) of u_r*h_r[f],
// v_r*h_r[f], built in LDS via segmented scan. h chunk scattered into sorted
// order at load via inverse permutation. ~110 KB LDS -> 1 block/CU.
// L1 (OUTBF=1): grid (16, 8=hy, 8=bz); L2: grid (16, 1, 8).
// ---------------------------------------------------------------------------
template <int OUTBF>
__global__ __launch_bounds__(256) void attn_sorted(
    const unsigned short* __restrict__ hT, const unsigned short* __restrict__ invS,
    const float2* __restrict__ uvS, const unsigned short* __restrict__ tS,
    const float2* __restrict__ cS, float* __restrict__ outf,
    unsigned short* __restrict__ outb)
{
    __shared__ __align__(16) unsigned short hperm[8][1036];
    __shared__ __align__(16) unsigned short invl[1024];
    __shared__ __align__(16) unsigned short tl[1024];
    __shared__ __align__(16) float2 uvl[1024];
    __shared__ __align__(16) float2 cabl[1024];
    __shared__ float CuT[1025][9];
    __shared__ float CvT[1025][9];
    __shared__ float segU[32][8];
    __shared__ float segV[32][8];

    const int tid = threadIdx.x;
    const int f0 = blockIdx.x * 8;
    const int hy = OUTBF ? blockIdx.y : 0;
    const int bz = blockIdx.z;
    const int hb = hy * 8 + bz;
    const size_t sb = (size_t)hb * 1024;

    // per-slice small arrays
    {
        if (tid < 128) {
            ((uint4*)invl)[tid] = ((const uint4*)(invS + sb))[tid];
            ((uint4*)tl)[tid]   = ((const uint4*)(tS + sb))[tid];
        }
        ((uint4*)uvl)[tid]        = ((const uint4*)(uvS + sb))[tid];
        ((uint4*)uvl)[tid + 256]  = ((const uint4*)(uvS + sb))[tid + 256];
        ((uint4*)cabl)[tid]       = ((const uint4*)(cS + sb))[tid];
        ((uint4*)cabl)[tid + 256] = ((const uint4*)(cS + sb))[tid + 256];
    }
    __syncthreads();   // invl ready

    // h rows f0..f0+7 scattered into sorted-rank order
    const unsigned short* gsrc = hT + ((size_t)(hy * 128 + f0)) * 8192 + bz * 1024;
#pragma unroll
    for (int e = 0; e < 4; ++e) {
        int c = tid + 256 * e;
        int row = c >> 7, col = (c & 127) * 8;
        uint4 v = *(const uint4*)(gsrc + (size_t)row * 8192 + col);
        const unsigned short* sv = (const unsigned short*)&v;
#pragma unroll
        for (int q = 0; q < 8; ++q)
            hperm[row][invl[col + q]] = sv[q];
    }
    __syncthreads();

    // segmented exclusive scan: thread (f = tid&7, seg = tid>>3)
    {
        const int f = tid & 7, seg = tid >> 3;
        const int r0 = seg * 32;
        float su = 0.f, sv = 0.f;
#pragma unroll 4
        for (int k = 0; k < 32; ++k) {
            int r = r0 + k;
            float hv = bfs(hperm[f][r]);
            float2 uvr = uvl[r];
            CuT[r][f] = su;
            CvT[r][f] = sv;
            su = fmaf(uvr.x, hv, su);
            sv = fmaf(uvr.y, hv, sv);
        }
        segU[seg][f] = su;
        segV[seg][f] = sv;
    }
    __syncthreads();
    if (tid < 8) {
        const int f = tid;
        float su = 0.f, sv = 0.f;
        for (int g = 0; g < 32; ++g) {
            float tu = segU[g][f], tv = segV[g][f];
            segU[g][f] = su; segV[g][f] = sv;
            su += tu; sv += tv;
        }
        CuT[1024][f] = su;
        CvT[1024][f] = sv;
    }
    __syncthreads();
    {
        const int f = tid & 7, seg = tid >> 3;
        const int r0 = seg * 32;
        float ou = segU[seg][f], ov = segV[seg][f];
#pragma unroll 4
        for (int k = 0; k < 32; ++k) {
            CuT[r0 + k][f] += ou;
            CvT[r0 + k][f] += ov;
        }
    }
    __syncthreads();

    // lookup: thread (f = tid&7, ig = tid>>3) handles i = ig*32..+31
    {
        const int f = tid & 7, ig = tid >> 3;
        const float cu_tot = CuT[1024][f];
#pragma unroll 4
        for (int k = 0; k < 32; ++k) {
            int i = ig * 32 + k;
            int t = tl[i];
            float2 c = cabl[i];
            float ov = c.x * (cu_tot - CuT[t][f]) + c.y * CvT[t][f];
            ov = elu1(ov);
            if (OUTBF) {
                outb[(size_t)(bz * 1024 + i) * 1024 + hy * 128 + f0 + f] = f2bf(ov);
            } else {
                ov = elu1(ov);
                outf[(size_t)(bz * 1024 + i) * 128 + f0 + f] = ov;
            }
        }
    }
}

// ---------------------------------------------------------------------------
// B=8, N=1024, D=256, H=8, F=128
// ---------------------------------------------------------------------------
extern "C" void kernel_launch(void* const* d_in, const int* in_sizes, int n_in,
                              void* d_out, int out_size, void* d_ws, size_t ws_size,
                              hipStream_t stream)
{
    const float* x  = (const float*)d_in[0];
    const float* Wh = (const float*)d_in[2];
    const float* ah = (const float*)d_in[3];
    const float* Wo = (const float*)d_in[4];
    const float* ao = (const float*)d_in[5];
    float* out = (float*)d_out;

    unsigned short* xb  = (unsigned short*)d_ws;       // [8192][256]
    unsigned short* WhT = xb + 2097152;                // [1024][256]
    unsigned short* WoT = WhT + 262144;                // [128][1024]
    unsigned short* h1T = WoT + 131072;                // [8][128][8192]
    unsigned short* xcb = h1T + 8388608;               // [8192][1024]
    unsigned short* h2T = xcb + 8388608;               // [128][8192]
    unsigned short* invA = h2T + 1048576;              // [64][1024] ushort
    unsigned short* tA   = invA + 65536;               // [64][1024]
    unsigned short* invB = tA + 65536;                 // [8][1024]
    unsigned short* tB   = invB + 8192;                // [8][1024]
    float* f1a  = (float*)(tB + 8192);                 // [8][8192]
    float* f2a  = f1a + 65536;                         // [8][8192]
    float* f1b  = f2a + 65536;                         // [8192]
    float* f2b  = f1b + 8192;                          // [8192]
    float2* uvA = (float2*)(f2b + 8192);               // [64][1024] float2
    float2* cA  = uvA + 65536;                         // [64][1024]
    float2* uvB = cA + 65536;                          // [8][1024]
    float2* cB  = uvB + 8192;                          // [8][1024]

    // prep: weight transposes + x->bf16 in one launch
    prep_all<<<2336, 256, 0, stream>>>(x, Wh, Wo, xb, WhT, WoT);

    // Layer 1
    gemm_t<64, 128, 32, 64, 1><<<dim3(128, 8), 256, 0, stream>>>(
        xb, WhT, h1T, 256, ah, f1a, f2a);
    sort_prep<<<64, 256, 0, stream>>>(f1a, f2a, invA, uvA, tA, cA);
    attn_sorted<1><<<dim3(16, 8, 8), 256, 0, stream>>>(
        h1T, invA, uvA, tA, cA, nullptr, xcb);

    // Layer 2
    gemm_t<64, 128, 32, 64, 1><<<dim3(128, 1), 256, 0, stream>>>(
        xcb, WoT, h2T, 1024, ao, f1b, f2b);
    sort_prep<<<8, 256, 0, stream>>>(f1b, f2b, invB, uvB, tB, cB);
    attn_sorted<0><<<dim3(16, 1, 8), 256, 0, stream>>>(
        h2T, invB, uvB, tB, cB, out, nullptr);
}